// Round 1
// 487.748 us; speedup vs baseline: 1.0213x; 1.0213x over previous
//
#include <hip/hip_runtime.h>

// Problem constants (match reference setup_inputs)
#define M_NODES 100000
#define MPAD    100096   // 782 * 128 — padded rows for the 128-row GEMM tile
#define K_DIM   512
#define N_DIM   128
#define NUM_EDGES 3200000

// Two-level bucketing
#define RSHIFT  6                 // 64 rows per bucket
#define ROWS_PB 64
#define NBUCK   1563              // ceil(100000 / 64)
#define BCAP    2432              // mean 2048 + ~8.5 sigma slack
#define EPW     4096              // edges per workgroup in bin part
#define NAPPEND ((NUM_EDGES + EPW - 1) / EPW)  // 782
#define GEMM_BLOCKS (MPAD / 128)               // 782

// GEMM staging: BK=32 fp32 LDS tiles, double buffered (2 x 16 KB)
#define BK      32
#define KSTEPS  (K_DIM / BK)      // 16

typedef __bf16 bf16x8 __attribute__((ext_vector_type(8)));
typedef float f32x16 __attribute__((ext_vector_type(16)));
typedef unsigned short ushort8 __attribute__((ext_vector_type(8)));
typedef unsigned int uint32;

typedef __attribute__((address_space(1))) const unsigned int gas_u32;
typedef __attribute__((address_space(3))) unsigned int las_u32;

// fp32 -> bf16 round-to-nearest-even
__device__ __forceinline__ unsigned short f2bf(float f) {
  uint32 u = __float_as_uint(f);
  u = (u + 0x7FFFu + ((u >> 16) & 1u)) >> 16;
  return (unsigned short)u;
}

__device__ __forceinline__ float bf_lo(uint32 m) {
  return __uint_as_float(m << 16);
}
__device__ __forceinline__ float bf_hi(uint32 m) {
  return __uint_as_float(m & 0xFFFF0000u);
}

// ---------------------------------------------------------------------------
// Kernel 0: swizzle W into bf16 B-fragment order for v_mfma_f32_32x32x16_bf16
// (flat: Wf[((ks*4 + ng)*64 + lane)*8 + j]) and zero gcursor.
// ---------------------------------------------------------------------------
__global__ __launch_bounds__(256) void wfrag_kernel(
    const float* __restrict__ W, unsigned short* __restrict__ Wf,
    int* __restrict__ gcursor) {
  const int t = blockIdx.x * 256 + threadIdx.x;  // 65536 total
  const int j = t & 7;
  const int lane = (t >> 3) & 63;
  const int ng = (t >> 9) & 3;
  const int ks = t >> 11;  // 0..31
  const int k = ks * 16 + ((lane >> 5) << 3) + j;
  const int n = (ng << 5) + (lane & 31);
  Wf[t] = f2bf(W[k * N_DIM + n]);
  if (t < NBUCK) gcursor[t] = 0;
}

// ---------------------------------------------------------------------------
// GEMM A-tile staging: async DMA global->LDS (width=16), fp32, swizzled.
// LDS tile layout: [128 rows][32 floats] = 16 KB, row = 8 chunks of 16 B,
// chunk stored at (chunk ^ (row&7)) via pre-swizzled GLOBAL source address
// (global_load_lds dest is linear: wave-uniform base + lane*16).
// ---------------------------------------------------------------------------
__device__ __forceinline__ void stage_tile(float* dst,
                                           const float* __restrict__ x,
                                           int row0, int k0, int w, int lane) {
#pragma unroll
  for (int i = 0; i < 4; ++i) {
    const int seg = i * 4 + w;               // 16 segments x 1 KB
    const int d = seg * 1024 + lane * 16;    // linear byte offset in tile
    const int row = d >> 7;                  // 128 B per row
    const int ch = (d >> 4) & 7;
    const int sch = ch ^ (row & 7);          // inverse-swizzled source chunk
    int gr = row0 + row;
    if (gr >= M_NODES) gr = M_NODES - 1;
    const float* src = x + (size_t)gr * K_DIM + k0 + sch * 4;
    __builtin_amdgcn_global_load_lds((gas_u32*)src,
                                     (las_u32*)(dst + seg * 256), 16, 0, 0);
  }
}

// Read one A-fragment (8 bf16) for mfma_f32_32x32x16: row r, k-sub ks, half hi.
// Applies the same XOR on the ds_read side; converts fp32->bf16 in-register.
__device__ __forceinline__ bf16x8 read_a_frag(const float* As, int r, int ks,
                                              int hi) {
  const int c0 = ks * 4 + hi * 2;
  const int sw = r & 7;
  const float4 f0 = *(const float4*)(As + r * 32 + ((c0 ^ sw) << 2));
  const float4 f1 = *(const float4*)(As + r * 32 + (((c0 + 1) ^ sw) << 2));
  ushort8 u;
  u[0] = f2bf(f0.x); u[1] = f2bf(f0.y); u[2] = f2bf(f0.z); u[3] = f2bf(f0.w);
  u[4] = f2bf(f1.x); u[5] = f2bf(f1.y); u[6] = f2bf(f1.z); u[7] = f2bf(f1.w);
  return __builtin_bit_cast(bf16x8, u);
}

// ---------------------------------------------------------------------------
// GEMM body: xp(bf16, row-major 128) = x @ W, 128x128 per block, 4 waves.
// Async-DMA double-buffered A staging, ONE barrier per k-step.
// ---------------------------------------------------------------------------
__device__ __forceinline__ void gemm_body(int bx, char* smem,
                                          const float* __restrict__ x,
                                          const unsigned short* __restrict__ Wf,
                                          unsigned short* __restrict__ xp) {
  float* A0 = (float*)smem;             // 16 KB
  float* A1 = (float*)(smem + 16384);   // 16 KB

  const int tid = threadIdx.x;
  const int w = tid >> 6;
  const int lane = tid & 63;
  const int l31 = lane & 31;
  const int lhi = lane >> 5;
  const int row0 = bx * 128;
  const int r = w * 32 + l31;

  f32x16 acc[4] = {};

  stage_tile(A0, x, row0, 0, w, lane);
  __syncthreads();  // compiler emits vmcnt(0) drain before s_barrier

  for (int t = 0; t < KSTEPS; ++t) {
    float* cur = (t & 1) ? A1 : A0;
    float* nxt = (t & 1) ? A0 : A1;
    // Issue next tile's DMA first: in flight across this step's compute.
    // nxt was last read at step t-1, whose barrier all waves have passed.
    if (t + 1 < KSTEPS) stage_tile(nxt, x, row0, (t + 1) * BK, w, lane);

    const int ksg0 = t * 2;  // global 16-wide k-subtile index
#pragma unroll
    for (int ks = 0; ks < 2; ++ks) {
      const bf16x8 a = read_a_frag(cur, r, ks, lhi);
      const ushort8* bp =
          (const ushort8*)(Wf) + ((size_t)(ksg0 + ks) * 4 * 64 + lane);
#pragma unroll
      for (int ng = 0; ng < 4; ++ng) {
        const bf16x8 b = __builtin_bit_cast(bf16x8, bp[(size_t)ng * 64]);
        acc[ng] =
            __builtin_amdgcn_mfma_f32_32x32x16_bf16(a, b, acc[ng], 0, 0, 0);
      }
    }
    __syncthreads();  // drains this step's DMA; frees cur for overwrite
  }

  // C/D layout: col = lane&31, row = (reg&3) + 8*(reg>>2) + 4*(lane>>5)
  const int rbase = row0 + w * 32 + 4 * lhi;
#pragma unroll
  for (int ng = 0; ng < 4; ++ng) {
    const int cc = (ng << 5) + l31;
#pragma unroll
    for (int reg = 0; reg < 16; ++reg) {
      const int rr = rbase + (reg & 3) + 8 * (reg >> 2);
      xp[(size_t)rr * N_DIM + cc] = f2bf(acc[ng][reg]);
    }
  }
}

// ---------------------------------------------------------------------------
// Bin body: LDS-aggregated append of uint2 records {col<<6|rl, fp32 val bits}
// into coarse bucket regions; global atomics only for chunk reservation.
// ---------------------------------------------------------------------------
__device__ __forceinline__ int tag_edge(int r, int* lcnt) {
  const int b = r >> RSHIFT;
  const int s = atomicAdd(&lcnt[b], 1);
  return (b << 18) | (s << 6) | (r & (ROWS_PB - 1));  // b:11b, s:12b, rl:6b
}

__device__ __forceinline__ void emit_edge(int p, int col, float v,
                                          const int* lbase,
                                          uint2* __restrict__ buckets) {
  const int b = (int)((unsigned)p >> 18);
  const int idx = lbase[b] + ((p >> 6) & 0xFFF);
  if (idx < BCAP)
    buckets[(size_t)b * BCAP + idx] = make_uint2(
        ((uint32)col << 6) | (uint32)(p & (ROWS_PB - 1)), __float_as_uint(v));
}

__device__ __forceinline__ void bin_body(int bx, char* smem,
                                         const int* __restrict__ erow,
                                         const int* __restrict__ ecol,
                                         const float* __restrict__ eval,
                                         int* __restrict__ gcursor,
                                         uint2* __restrict__ buckets) {
  int* lcnt = (int*)smem;            // 6252 B
  int* lbase = (int*)(smem + 6912);  // 6252 B
  const int tid = threadIdx.x;
  for (int i = tid; i < NBUCK; i += 256) lcnt[i] = 0;
  __syncthreads();

  const int base = bx * EPW;
  int pk[16];
#pragma unroll
  for (int c = 0; c < 4; ++c) {
    const int e0 = base + c * 1024 + tid * 4;
    if (e0 < NUM_EDGES) {  // NUM_EDGES % 4 == 0 -> whole int4 in or out
      const int4 r4 = *(const int4*)(erow + e0);
      pk[c * 4 + 0] = tag_edge(r4.x, lcnt);
      pk[c * 4 + 1] = tag_edge(r4.y, lcnt);
      pk[c * 4 + 2] = tag_edge(r4.z, lcnt);
      pk[c * 4 + 3] = tag_edge(r4.w, lcnt);
    }
  }
  __syncthreads();

  for (int i = tid; i < NBUCK; i += 256) {
    const int c = lcnt[i];
    lbase[i] = c ? atomicAdd(&gcursor[i], c) : 0;
  }
  __syncthreads();

#pragma unroll
  for (int c = 0; c < 4; ++c) {
    const int e0 = base + c * 1024 + tid * 4;
    if (e0 < NUM_EDGES) {
      const int4 c4 = *(const int4*)(ecol + e0);
      const float4 v4 = *(const float4*)(eval + e0);
      emit_edge(pk[c * 4 + 0], c4.x, v4.x, lbase, buckets);
      emit_edge(pk[c * 4 + 1], c4.y, v4.y, lbase, buckets);
      emit_edge(pk[c * 4 + 2], c4.z, v4.z, lbase, buckets);
      emit_edge(pk[c * 4 + 3], c4.w, v4.w, lbase, buckets);
    }
  }
}

// ---------------------------------------------------------------------------
// Kernel 1: fused GEMM + bin_append (independent work, block-range split).
// ---------------------------------------------------------------------------
__global__ __launch_bounds__(256) void gemm_bin_kernel(
    const float* __restrict__ x, const unsigned short* __restrict__ Wf,
    unsigned short* __restrict__ xp, const int* __restrict__ erow,
    const int* __restrict__ ecol, const float* __restrict__ eval,
    int* __restrict__ gcursor, uint2* __restrict__ buckets) {
  __shared__ __align__(16) char smem[32768];
  if (blockIdx.x < GEMM_BLOCKS) {
    gemm_body(blockIdx.x, smem, x, Wf, xp);
  } else {
    bin_body(blockIdx.x - GEMM_BLOCKS, smem, erow, ecol, eval, gcursor,
             buckets);
  }
}

// ---------------------------------------------------------------------------
// Kernel 2: bucket_gather — one wg per 64-row bucket (round-5 proven design).
// Build per-row CSR in LDS with INTEGER atomics (native ds_add_rtn_u32),
// then each wave gathers its rows' edges (256 B coalesced xp row, unroll-4),
// register accumulate, fused ReLU, write-once.
// ---------------------------------------------------------------------------
__global__ __launch_bounds__(256, 8) void bucket_gather_kernel(
    const unsigned short* __restrict__ xp, const int* __restrict__ gcursor,
    const uint2* __restrict__ buckets, float* __restrict__ out) {
  __shared__ uint2 eds[BCAP];            // 19456 B
  __shared__ int rbase[ROWS_PB + 1];
  __shared__ int rcur[ROWS_PB];
  __shared__ int stmp[ROWS_PB];

  const int b = blockIdx.x;
  const int tid = threadIdx.x;
  int n = gcursor[b];
  if (n > BCAP) n = BCAP;

  if (tid < ROWS_PB) rcur[tid] = 0;
  __syncthreads();

  const uint2* bk = buckets + (size_t)b * BCAP;
  // pass 1: per-row counts (integer LDS atomics — native)
  for (int i = tid; i < n; i += 256) atomicAdd(&rcur[bk[i].x & 63], 1);
  __syncthreads();

  // scan 64 counters -> rbase (exclusive, rbase[64] = n)
  if (tid < ROWS_PB) stmp[tid] = rcur[tid];
  __syncthreads();
  for (int off = 1; off < ROWS_PB; off <<= 1) {
    int v = 0, a = 0;
    if (tid < ROWS_PB) {
      v = stmp[tid];
      if (tid >= off) a = stmp[tid - off];
    }
    __syncthreads();
    if (tid < ROWS_PB) stmp[tid] = v + a;
    __syncthreads();
  }
  if (tid < ROWS_PB) {
    rbase[tid + 1] = stmp[tid];
    rcur[tid] = 0;
  }
  if (tid == 0) rbase[0] = 0;
  __syncthreads();

  // pass 2: scatter edges into row-sorted LDS order
  for (int i = tid; i < n; i += 256) {
    const uint2 e = bk[i];
    const int rl = e.x & 63;
    const int pos = rbase[rl] + atomicAdd(&rcur[rl], 1);
    eds[pos] = e;
  }
  __syncthreads();

  // gather: wave w handles rows w, w+4, ... (16 rows/wave)
  const int wv = tid >> 6;
  const int lane = tid & 63;
  const uint32* xpl = (const uint32*)xp + lane;

  for (int rl = wv; rl < ROWS_PB; rl += 4) {
    const int row = (b << RSHIFT) + rl;
    if (row >= M_NODES) break;
    const int s = rbase[rl];
    const int e = rbase[rl + 1];

    float ax0 = 0.f, ay0 = 0.f, ax1 = 0.f, ay1 = 0.f;
    float ax2 = 0.f, ay2 = 0.f, ax3 = 0.f, ay3 = 0.f;
    int i = s;
    for (; i + 3 < e; i += 4) {
      const uint2 e0 = eds[i];
      const uint2 e1 = eds[i + 1];
      const uint2 e2 = eds[i + 2];
      const uint2 e3 = eds[i + 3];
      const uint32 m0 = xpl[(size_t)(e0.x >> 6) * 64];
      const uint32 m1 = xpl[(size_t)(e1.x >> 6) * 64];
      const uint32 m2 = xpl[(size_t)(e2.x >> 6) * 64];
      const uint32 m3 = xpl[(size_t)(e3.x >> 6) * 64];
      const float v0 = __uint_as_float(e0.y);
      const float v1 = __uint_as_float(e1.y);
      const float v2 = __uint_as_float(e2.y);
      const float v3 = __uint_as_float(e3.y);
      ax0 += v0 * bf_lo(m0); ay0 += v0 * bf_hi(m0);
      ax1 += v1 * bf_lo(m1); ay1 += v1 * bf_hi(m1);
      ax2 += v2 * bf_lo(m2); ay2 += v2 * bf_hi(m2);
      ax3 += v3 * bf_lo(m3); ay3 += v3 * bf_hi(m3);
    }
    for (; i < e; ++i) {
      const uint2 e0 = eds[i];
      const uint32 m0 = xpl[(size_t)(e0.x >> 6) * 64];
      const float v0 = __uint_as_float(e0.y);
      ax0 += v0 * bf_lo(m0);
      ay0 += v0 * bf_hi(m0);
    }

    float2 r;
    r.x = fmaxf((ax0 + ax1) + (ax2 + ax3), 0.f);
    r.y = fmaxf((ay0 + ay1) + (ay2 + ay3), 0.f);
    *(float2*)(out + (size_t)row * N_DIM + lane * 2) = r;
  }
}

extern "C" void kernel_launch(void* const* d_in, const int* in_sizes, int n_in,
                              void* d_out, int out_size, void* d_ws,
                              size_t ws_size, hipStream_t stream) {
  const float* x = (const float*)d_in[0];     // [100000, 512]
  const float* W = (const float*)d_in[1];     // [512, 128]
  const int* erow = (const int*)d_in[2];      // [3.2M]
  const int* ecol = (const int*)d_in[3];      // [3.2M]
  const float* eval = (const float*)d_in[4];  // [3.2M]
  float* out = (float*)d_out;                 // [100000, 128]

  char* wsb = (char*)d_ws;
  size_t off = 0;
  auto alloc = [&](size_t bytes) {
    char* p = wsb + off;
    off = (off + bytes + 511) & ~(size_t)511;
    return p;
  };
  unsigned short* xp =
      (unsigned short*)alloc((size_t)MPAD * N_DIM * sizeof(unsigned short));
  unsigned short* Wf =
      (unsigned short*)alloc((size_t)K_DIM * N_DIM * sizeof(unsigned short));
  int* gcursor = (int*)alloc((size_t)NBUCK * sizeof(int));
  uint2* buckets = (uint2*)alloc((size_t)NBUCK * BCAP * sizeof(uint2));
  (void)ws_size;

  // W swizzle + gcursor zeroing (gcursor poisoned 0xAA every call)
  wfrag_kernel<<<(K_DIM * N_DIM) / 256, 256, 0, stream>>>(W, Wf, gcursor);

  // Fused GEMM + bucket append
  gemm_bin_kernel<<<GEMM_BLOCKS + NAPPEND, 256, 0, stream>>>(
      x, Wf, xp, erow, ecol, eval, gcursor, buckets);

  // Per-bucket CSR build + gather + ReLU (write-once)
  bucket_gather_kernel<<<NBUCK, 256, 0, stream>>>(xp, gcursor, buckets, out);
}

// Round 2
// 474.063 us; speedup vs baseline: 1.0508x; 1.0289x over previous
//
#include <hip/hip_runtime.h>

// Problem constants (match reference setup_inputs)
#define M_NODES 100000
#define MPAD    100096   // 782 * 128 — padded rows for the 128-row GEMM tile
#define K_DIM   512
#define N_DIM   128
#define NUM_EDGES 3200000

// Two-level bucketing
#define RSHIFT  6                 // 64 rows per bucket
#define ROWS_PB 64
#define NBUCK   1563              // ceil(100000 / 64)
#define BCAP    2432              // mean 2048 + ~8.5 sigma slack
#define EPW     4096              // edges per workgroup in bin part
#define NAPPEND ((NUM_EDGES + EPW - 1) / EPW)  // 782
#define GEMM_BLOCKS (MPAD / 128)               // 782

// GEMM staging: BK=32 k-steps; per step stage A fp32 [128][32] (16 KB) and
// the W bf16 fragment panel for that step (8 KB). Double buffered: 48 KB.
#define BK      32
#define KSTEPS  (K_DIM / BK)      // 16
#define ABYTES  16384
#define WBYTES  8192
#define BUFBYTES (ABYTES + WBYTES)  // 24576

typedef __bf16 bf16x8 __attribute__((ext_vector_type(8)));
typedef float f32x16 __attribute__((ext_vector_type(16)));
typedef unsigned short ushort8 __attribute__((ext_vector_type(8)));
typedef unsigned int uint32;

typedef __attribute__((address_space(1))) const unsigned int gas_u32;
typedef __attribute__((address_space(3))) unsigned int las_u32;

// fp32 -> bf16 round-to-nearest-even
__device__ __forceinline__ unsigned short f2bf(float f) {
  uint32 u = __float_as_uint(f);
  u = (u + 0x7FFFu + ((u >> 16) & 1u)) >> 16;
  return (unsigned short)u;
}

__device__ __forceinline__ float bf_lo(uint32 m) {
  return __uint_as_float(m << 16);
}
__device__ __forceinline__ float bf_hi(uint32 m) {
  return __uint_as_float(m & 0xFFFF0000u);
}

// ---------------------------------------------------------------------------
// Kernel 0: swizzle W into bf16 B-fragment order for v_mfma_f32_32x32x16_bf16
// (flat: Wf[((ks*4 + ng)*64 + lane)*8 + j]) and zero gcursor.
// Step-t panel = ushorts [t*4096, (t+1)*4096) — contiguous, DMA-friendly.
// ---------------------------------------------------------------------------
__global__ __launch_bounds__(256) void wfrag_kernel(
    const float* __restrict__ W, unsigned short* __restrict__ Wf,
    int* __restrict__ gcursor) {
  const int t = blockIdx.x * 256 + threadIdx.x;  // 65536 total
  const int j = t & 7;
  const int lane = (t >> 3) & 63;
  const int ng = (t >> 9) & 3;
  const int ks = t >> 11;  // 0..31
  const int k = ks * 16 + ((lane >> 5) << 3) + j;
  const int n = (ng << 5) + (lane & 31);
  Wf[t] = f2bf(W[k * N_DIM + n]);
  if (t < NBUCK) gcursor[t] = 0;
}

// ---------------------------------------------------------------------------
// A-tile staging: async DMA global->LDS (width=16), fp32, swizzled.
// LDS tile layout: [128 rows][32 floats] = 16 KB, row = 8 chunks of 16 B,
// chunk stored at (chunk ^ (row&7)) via pre-swizzled GLOBAL source address
// (global_load_lds dest is linear: wave-uniform base + lane*16). 4 loads/wave.
// ---------------------------------------------------------------------------
__device__ __forceinline__ void stage_a(float* dst,
                                        const float* __restrict__ x,
                                        int row0, int k0, int w, int lane) {
#pragma unroll
  for (int i = 0; i < 4; ++i) {
    const int seg = i * 4 + w;               // 16 segments x 1 KB
    const int d = seg * 1024 + lane * 16;    // linear byte offset in tile
    const int row = d >> 7;                  // 128 B per row
    const int ch = (d >> 4) & 7;
    const int sch = ch ^ (row & 7);          // inverse-swizzled source chunk
    int gr = row0 + row;
    if (gr >= M_NODES) gr = M_NODES - 1;
    const float* src = x + (size_t)gr * K_DIM + k0 + sch * 4;
    __builtin_amdgcn_global_load_lds((gas_u32*)src,
                                     (las_u32*)(dst + seg * 256), 16, 0, 0);
  }
}

// W panel staging: linear 8 KB copy of step t's fragment panel. 2 loads/wave.
__device__ __forceinline__ void stage_w(unsigned short* dst,
                                        const unsigned short* __restrict__ Wf,
                                        int t, int w, int lane) {
#pragma unroll
  for (int i = 0; i < 2; ++i) {
    const int seg = i * 4 + w;               // 8 segments x 1 KB
    const unsigned short* src =
        Wf + (size_t)t * 4096 + seg * 512 + lane * 8;
    __builtin_amdgcn_global_load_lds((gas_u32*)src,
                                     (las_u32*)(dst + seg * 512), 16, 0, 0);
  }
}

// Read one A-fragment (8 bf16) for mfma_f32_32x32x16: row r, k-sub ks, half hi.
// Applies the same XOR on the ds_read side; converts fp32->bf16 in-register.
__device__ __forceinline__ bf16x8 read_a_frag(const float* As, int r, int ks,
                                              int hi) {
  const int c0 = ks * 4 + hi * 2;
  const int sw = r & 7;
  const float4 f0 = *(const float4*)(As + r * 32 + ((c0 ^ sw) << 2));
  const float4 f1 = *(const float4*)(As + r * 32 + (((c0 + 1) ^ sw) << 2));
  ushort8 u;
  u[0] = f2bf(f0.x); u[1] = f2bf(f0.y); u[2] = f2bf(f0.z); u[3] = f2bf(f0.w);
  u[4] = f2bf(f1.x); u[5] = f2bf(f1.y); u[6] = f2bf(f1.z); u[7] = f2bf(f1.w);
  return __builtin_bit_cast(bf16x8, u);
}

// ---------------------------------------------------------------------------
// GEMM body: xp(bf16, row-major 128) = x @ W, 128x128 per block, 4 waves.
// T3/T4 schedule: raw s_barrier + counted vmcnt(6) — the staging DMA for
// step t+1 stays in flight across the whole of step t's compute (never
// drained to 0 in the main loop). Only vmem ops in the loop are the 6 DMAs.
// ---------------------------------------------------------------------------
__device__ __forceinline__ void gemm_body(int bx, char* smem,
                                          const float* __restrict__ x,
                                          const unsigned short* __restrict__ Wf,
                                          unsigned short* __restrict__ xp) {
  float* A0 = (float*)smem;
  unsigned short* W0 = (unsigned short*)(smem + ABYTES);
  float* A1 = (float*)(smem + BUFBYTES);
  unsigned short* W1 = (unsigned short*)(smem + BUFBYTES + ABYTES);

  const int tid = threadIdx.x;
  const int w = tid >> 6;
  const int lane = tid & 63;
  const int l31 = lane & 31;
  const int lhi = lane >> 5;
  const int row0 = bx * 128;
  const int r = w * 32 + l31;

  f32x16 acc[4] = {};

  // Prologue: 6 DMAs for tile 0 in flight.
  stage_a(A0, x, row0, 0, w, lane);
  stage_w(W0, Wf, 0, w, lane);

  for (int t = 0; t < KSTEPS; ++t) {
    float* Ac = (t & 1) ? A1 : A0;
    unsigned short* Wc = (t & 1) ? W1 : W0;
    if (t + 1 < KSTEPS) {
      // Issue next tile's 6 DMAs; they ride across both barriers and the
      // compute below. Overwrite-safety: buffer (t+1)&1 was last read at
      // step t-1, whose trailing barrier every wave has passed.
      float* An = (t & 1) ? A0 : A1;
      unsigned short* Wn = (t & 1) ? W0 : W1;
      stage_a(An, x, row0, (t + 1) * BK, w, lane);
      stage_w(Wn, Wf, t + 1, w, lane);
      // 12 outstanding -> drain the 6 oldest (tile t), keep tile t+1 flying.
      asm volatile("s_waitcnt vmcnt(6)" ::: "memory");
    } else {
      asm volatile("s_waitcnt vmcnt(0)" ::: "memory");
    }
    __builtin_amdgcn_s_barrier();  // tile t fully in LDS for all waves

#pragma unroll
    for (int ks = 0; ks < 2; ++ks) {
      const bf16x8 a = read_a_frag(Ac, r, ks, lhi);
      const ushort8* bp = (const ushort8*)Wc + (size_t)ks * 4 * 64 + lane;
#pragma unroll
      for (int ng = 0; ng < 4; ++ng) {
        const bf16x8 b = __builtin_bit_cast(bf16x8, bp[(size_t)ng * 64]);
        acc[ng] =
            __builtin_amdgcn_mfma_f32_32x32x16_bf16(a, b, acc[ng], 0, 0, 0);
      }
    }
    __builtin_amdgcn_s_barrier();  // all waves done reading tile t
  }

  // C/D layout: col = lane&31, row = (reg&3) + 8*(reg>>2) + 4*(lane>>5)
  const int rbase = row0 + w * 32 + 4 * lhi;
#pragma unroll
  for (int ng = 0; ng < 4; ++ng) {
    const int cc = (ng << 5) + l31;
#pragma unroll
    for (int reg = 0; reg < 16; ++reg) {
      const int rr = rbase + (reg & 3) + 8 * (reg >> 2);
      xp[(size_t)rr * N_DIM + cc] = f2bf(acc[ng][reg]);
    }
  }
}

// ---------------------------------------------------------------------------
// Bin body: LDS-aggregated append of uint2 records {col<<6|rl, fp32 val bits}
// into coarse bucket regions; global atomics only for chunk reservation.
// ---------------------------------------------------------------------------
__device__ __forceinline__ int tag_edge(int r, int* lcnt) {
  const int b = r >> RSHIFT;
  const int s = atomicAdd(&lcnt[b], 1);
  return (b << 18) | (s << 6) | (r & (ROWS_PB - 1));  // b:11b, s:12b, rl:6b
}

__device__ __forceinline__ void emit_edge(int p, int col, float v,
                                          const int* lbase,
                                          uint2* __restrict__ buckets) {
  const int b = (int)((unsigned)p >> 18);
  const int idx = lbase[b] + ((p >> 6) & 0xFFF);
  if (idx < BCAP)
    buckets[(size_t)b * BCAP + idx] = make_uint2(
        ((uint32)col << 6) | (uint32)(p & (ROWS_PB - 1)), __float_as_uint(v));
}

__device__ __forceinline__ void bin_body(int bx, char* smem,
                                         const int* __restrict__ erow,
                                         const int* __restrict__ ecol,
                                         const float* __restrict__ eval,
                                         int* __restrict__ gcursor,
                                         uint2* __restrict__ buckets) {
  int* lcnt = (int*)smem;            // 6252 B
  int* lbase = (int*)(smem + 6912);  // 6252 B
  const int tid = threadIdx.x;
  for (int i = tid; i < NBUCK; i += 256) lcnt[i] = 0;
  __syncthreads();

  const int base = bx * EPW;
  int pk[16];
#pragma unroll
  for (int c = 0; c < 4; ++c) {
    const int e0 = base + c * 1024 + tid * 4;
    if (e0 < NUM_EDGES) {  // NUM_EDGES % 4 == 0 -> whole int4 in or out
      const int4 r4 = *(const int4*)(erow + e0);
      pk[c * 4 + 0] = tag_edge(r4.x, lcnt);
      pk[c * 4 + 1] = tag_edge(r4.y, lcnt);
      pk[c * 4 + 2] = tag_edge(r4.z, lcnt);
      pk[c * 4 + 3] = tag_edge(r4.w, lcnt);
    }
  }
  __syncthreads();

  for (int i = tid; i < NBUCK; i += 256) {
    const int c = lcnt[i];
    lbase[i] = c ? atomicAdd(&gcursor[i], c) : 0;
  }
  __syncthreads();

#pragma unroll
  for (int c = 0; c < 4; ++c) {
    const int e0 = base + c * 1024 + tid * 4;
    if (e0 < NUM_EDGES) {
      const int4 c4 = *(const int4*)(ecol + e0);
      const float4 v4 = *(const float4*)(eval + e0);
      emit_edge(pk[c * 4 + 0], c4.x, v4.x, lbase, buckets);
      emit_edge(pk[c * 4 + 1], c4.y, v4.y, lbase, buckets);
      emit_edge(pk[c * 4 + 2], c4.z, v4.z, lbase, buckets);
      emit_edge(pk[c * 4 + 3], c4.w, v4.w, lbase, buckets);
    }
  }
}

// ---------------------------------------------------------------------------
// Kernel 1: fused GEMM + bin_append (independent work, block-range split).
// ---------------------------------------------------------------------------
__global__ __launch_bounds__(256) void gemm_bin_kernel(
    const float* __restrict__ x, const unsigned short* __restrict__ Wf,
    unsigned short* __restrict__ xp, const int* __restrict__ erow,
    const int* __restrict__ ecol, const float* __restrict__ eval,
    int* __restrict__ gcursor, uint2* __restrict__ buckets) {
  __shared__ __align__(16) char smem[2 * BUFBYTES];  // 48 KB
  if (blockIdx.x < GEMM_BLOCKS) {
    gemm_body(blockIdx.x, smem, x, Wf, xp);
  } else {
    bin_body(blockIdx.x - GEMM_BLOCKS, smem, erow, ecol, eval, gcursor,
             buckets);
  }
}

// ---------------------------------------------------------------------------
// Kernel 2: bucket_gather — one wg per 64-row bucket (round-5 proven design).
// Build per-row CSR in LDS with INTEGER atomics (native ds_add_rtn_u32),
// then each wave gathers its rows' edges (256 B coalesced xp row, unroll-4),
// register accumulate, fused ReLU, write-once.
// ---------------------------------------------------------------------------
__global__ __launch_bounds__(256, 8) void bucket_gather_kernel(
    const unsigned short* __restrict__ xp, const int* __restrict__ gcursor,
    const uint2* __restrict__ buckets, float* __restrict__ out) {
  __shared__ uint2 eds[BCAP];            // 19456 B
  __shared__ int rbase[ROWS_PB + 1];
  __shared__ int rcur[ROWS_PB];
  __shared__ int stmp[ROWS_PB];

  const int b = blockIdx.x;
  const int tid = threadIdx.x;
  int n = gcursor[b];
  if (n > BCAP) n = BCAP;

  if (tid < ROWS_PB) rcur[tid] = 0;
  __syncthreads();

  const uint2* bk = buckets + (size_t)b * BCAP;
  // pass 1: per-row counts (integer LDS atomics — native)
  for (int i = tid; i < n; i += 256) atomicAdd(&rcur[bk[i].x & 63], 1);
  __syncthreads();

  // scan 64 counters -> rbase (exclusive, rbase[64] = n)
  if (tid < ROWS_PB) stmp[tid] = rcur[tid];
  __syncthreads();
  for (int off = 1; off < ROWS_PB; off <<= 1) {
    int v = 0, a = 0;
    if (tid < ROWS_PB) {
      v = stmp[tid];
      if (tid >= off) a = stmp[tid - off];
    }
    __syncthreads();
    if (tid < ROWS_PB) stmp[tid] = v + a;
    __syncthreads();
  }
  if (tid < ROWS_PB) {
    rbase[tid + 1] = stmp[tid];
    rcur[tid] = 0;
  }
  if (tid == 0) rbase[0] = 0;
  __syncthreads();

  // pass 2: scatter edges into row-sorted LDS order
  for (int i = tid; i < n; i += 256) {
    const uint2 e = bk[i];
    const int rl = e.x & 63;
    const int pos = rbase[rl] + atomicAdd(&rcur[rl], 1);
    eds[pos] = e;
  }
  __syncthreads();

  // gather: wave w handles rows w, w+4, ... (16 rows/wave)
  const int wv = tid >> 6;
  const int lane = tid & 63;
  const uint32* xpl = (const uint32*)xp + lane;

  for (int rl = wv; rl < ROWS_PB; rl += 4) {
    const int row = (b << RSHIFT) + rl;
    if (row >= M_NODES) break;
    const int s = rbase[rl];
    const int e = rbase[rl + 1];

    float ax0 = 0.f, ay0 = 0.f, ax1 = 0.f, ay1 = 0.f;
    float ax2 = 0.f, ay2 = 0.f, ax3 = 0.f, ay3 = 0.f;
    int i = s;
    for (; i + 3 < e; i += 4) {
      const uint2 e0 = eds[i];
      const uint2 e1 = eds[i + 1];
      const uint2 e2 = eds[i + 2];
      const uint2 e3 = eds[i + 3];
      const uint32 m0 = xpl[(size_t)(e0.x >> 6) * 64];
      const uint32 m1 = xpl[(size_t)(e1.x >> 6) * 64];
      const uint32 m2 = xpl[(size_t)(e2.x >> 6) * 64];
      const uint32 m3 = xpl[(size_t)(e3.x >> 6) * 64];
      const float v0 = __uint_as_float(e0.y);
      const float v1 = __uint_as_float(e1.y);
      const float v2 = __uint_as_float(e2.y);
      const float v3 = __uint_as_float(e3.y);
      ax0 += v0 * bf_lo(m0); ay0 += v0 * bf_hi(m0);
      ax1 += v1 * bf_lo(m1); ay1 += v1 * bf_hi(m1);
      ax2 += v2 * bf_lo(m2); ay2 += v2 * bf_hi(m2);
      ax3 += v3 * bf_lo(m3); ay3 += v3 * bf_hi(m3);
    }
    for (; i < e; ++i) {
      const uint2 e0 = eds[i];
      const uint32 m0 = xpl[(size_t)(e0.x >> 6) * 64];
      const float v0 = __uint_as_float(e0.y);
      ax0 += v0 * bf_lo(m0);
      ay0 += v0 * bf_hi(m0);
    }

    float2 r;
    r.x = fmaxf((ax0 + ax1) + (ax2 + ax3), 0.f);
    r.y = fmaxf((ay0 + ay1) + (ay2 + ay3), 0.f);
    *(float2*)(out + (size_t)row * N_DIM + lane * 2) = r;
  }
}

extern "C" void kernel_launch(void* const* d_in, const int* in_sizes, int n_in,
                              void* d_out, int out_size, void* d_ws,
                              size_t ws_size, hipStream_t stream) {
  const float* x = (const float*)d_in[0];     // [100000, 512]
  const float* W = (const float*)d_in[1];     // [512, 128]
  const int* erow = (const int*)d_in[2];      // [3.2M]
  const int* ecol = (const int*)d_in[3];      // [3.2M]
  const float* eval = (const float*)d_in[4];  // [3.2M]
  float* out = (float*)d_out;                 // [100000, 128]

  char* wsb = (char*)d_ws;
  size_t off = 0;
  auto alloc = [&](size_t bytes) {
    char* p = wsb + off;
    off = (off + bytes + 511) & ~(size_t)511;
    return p;
  };
  unsigned short* xp =
      (unsigned short*)alloc((size_t)MPAD * N_DIM * sizeof(unsigned short));
  unsigned short* Wf =
      (unsigned short*)alloc((size_t)K_DIM * N_DIM * sizeof(unsigned short));
  int* gcursor = (int*)alloc((size_t)NBUCK * sizeof(int));
  uint2* buckets = (uint2*)alloc((size_t)NBUCK * BCAP * sizeof(uint2));
  (void)ws_size;

  // W swizzle + gcursor zeroing (gcursor poisoned 0xAA every call)
  wfrag_kernel<<<(K_DIM * N_DIM) / 256, 256, 0, stream>>>(W, Wf, gcursor);

  // Fused GEMM + bucket append
  gemm_bin_kernel<<<GEMM_BLOCKS + NAPPEND, 256, 0, stream>>>(
      x, Wf, xp, erow, ecol, eval, gcursor, buckets);

  // Per-bucket CSR build + gather + ReLU (write-once)
  bucket_gather_kernel<<<NBUCK, 256, 0, stream>>>(xp, gcursor, buckets, out);
}